// Round 10
// baseline (29.320 us; speedup 1.0000x reference)
//
#include <hip/hip_runtime.h>
#include <hip/hip_fp16.h>
#include <stdint.h>

// out[8,8192] = x[8,8192] @ W.T, W[n,k] = nibble(Qidxs[n,k/8], INV[k%8]) - 7.5
// R10: B-path LDS eliminated. Lane (r16,u4) loads its 16 step-words directly
// global->VGPR (16 x dword @ +16B stride, one base, consumption-ordered).
// All B + 2 A-tiles issued upfront -> ~24 loads in flight per wave.
//   kernel 1: A-frag table [256 steps][33 slots][16B] in d_ws (slot 32 = zeros).
//   kernel 2: 512 blocks (16 n-rows) x 1024 threads (16 waves; wave owns 512 K =
//   16 x mfma_f32_16x16x32_f16). LDS only for the final 16-way reduce (8 KB).

typedef _Float16 half8 __attribute__((ext_vector_type(8)));
typedef float floatx4 __attribute__((ext_vector_type(4)));

union H2U { unsigned u; __half2 h; };
union V4H8 { uint4 u4; half8 h8; };

// nibbles {b, b+4} of w -> f16 pair {n_b, n_{b+4}} - 7.5, exact
__device__ __forceinline__ unsigned unpack_even(unsigned w, __half2 c1, __half2 c2) {
    H2U t; t.u = (w & 0x000F000Fu) | 0x64006400u;      // 1024 + n
    t.h = __hadd2(__hadd2(t.h, c1), c2);               // -1024, -7.5
    return t.u;
}
__device__ __forceinline__ unsigned unpack_odd(unsigned w, __half2 cs, __half2 cc) {
    H2U t; t.u = (w & 0x00F000F0u) | 0x64006400u;      // 1024 + 16n
    t.h = __hfma2(t.h, cs, cc);                        // /16, -71.5
    return t.u;
}

#define TPITCH 528                  // 33 slots x 16B per A-table step
#define NWV    16
#define LDS_BYTES (NWV * 128 * 4)   // 8192: reduce area only

// ---- kernel 1: A-frag table, one block per K-step (k-base = 32*S) ----
__global__ void build_atable(const float* __restrict__ x, char* __restrict__ tbl)
{
    const int S = blockIdx.x;           // 0..255
    const int t = threadIdx.x;          // 0..63; 0..32 active
    if (t > 32) return;
    uint4 v = make_uint4(0u, 0u, 0u, 0u);
    if (t < 32) {
        const int u = t >> 3, r = t & 7;            // slot = 8u + r = t
        const float4* x4 = (const float4*)x;        // 2048 float4 per b-row
        float4 fa = x4[r * 2048 + 8 * S + 2 * u];       // cols 32S+8u+0..3
        float4 fb = x4[r * 2048 + 8 * S + 2 * u + 1];   // cols 32S+8u+4..7
        H2U a0, a1, a2, a3;
        a0.h = __floats2half2_rn(fa.x, fa.y);
        a1.h = __floats2half2_rn(fa.z, fa.w);
        a2.h = __floats2half2_rn(fb.x, fb.y);
        a3.h = __floats2half2_rn(fb.z, fb.w);
        v = make_uint4(a0.u, a1.u, a2.u, a3.u);
    }
    const int slot = (t < 32) ? t : 32;             // slot 32 = zeros (pad rows)
    *(uint4*)(tbl + S * TPITCH + slot * 16) = v;
}

__global__ __launch_bounds__(1024, 4)
void hi4b_gemm(const char* __restrict__ atbl, const int* __restrict__ q,
               float* __restrict__ out)
{
    extern __shared__ char lds[];
    const int tid  = threadIdx.x;
    const int lane = tid & 63;
    const int wv   = tid >> 6;            // 0..15: K-window wv*512 (16 steps)
    const int n0   = blockIdx.x * 16;

    const int r16 = lane & 15;            // n row (B) / C col
    const int u4  = lane >> 4;            // k-group within step

    // ---- B: 16 consumption-ordered dword loads, all upfront ----
    // word for step s = Qidxs[n0+r16][wv*64 + 4s + u4]
    const unsigned* qw = (const unsigned*)q + (size_t)(n0 + r16) * 1024
                       + wv * 64 + u4;
    unsigned w[16];
    #pragma unroll
    for (int s = 0; s < 16; ++s)
        w[s] = qw[4 * s];                 // imm offsets 0,16,...,240 bytes

    // ---- A: table reads, 4-step tiles, 2 in flight ----
    const int  slot = (r16 < 8) ? (u4 * 8 + r16) : 32;
    const char* ap  = atbl + (size_t)(wv * 16) * TPITCH + slot * 16;

    uint4 T0[4], T1[4];
    auto refill = [&](uint4 (&T)[4], int t) {
        const char* p = ap + t * (4 * TPITCH);
        #pragma unroll
        for (int i = 0; i < 4; ++i)
            T[i] = *(const uint4*)(p + i * TPITCH);
    };
    refill(T0, 0);
    refill(T1, 1);

    const __half2 c1 = __floats2half2_rn(-1024.0f, -1024.0f);
    const __half2 c2 = __floats2half2_rn(-7.5f, -7.5f);
    const __half2 cs = __floats2half2_rn(0.0625f, 0.0625f);
    const __half2 cc = __floats2half2_rn(-71.5f, -71.5f);

    floatx4 acc = {0.0f, 0.0f, 0.0f, 0.0f};

    auto comp4 = [&](uint4 (&T)[4], int t) {
        #pragma unroll
        for (int i = 0; i < 4; ++i) {
            unsigned ww = w[4 * t + i];
            unsigned w8 = ww >> 8;
            V4H8 Bf;
            Bf.u4.x = unpack_even(ww, c1, c2);   // cols +0,+1 (nib 0,4)
            Bf.u4.y = unpack_odd (ww, cs, cc);   // cols +2,+3 (nib 1,5)
            Bf.u4.z = unpack_even(w8, c1, c2);   // cols +4,+5 (nib 2,6)
            Bf.u4.w = unpack_odd (w8, cs, cc);   // cols +6,+7 (nib 3,7)
            V4H8 A;  A.u4 = T[i];
            acc = __builtin_amdgcn_mfma_f32_16x16x32_f16(A.h8, Bf.h8, acc, 0, 0, 0);
        }
    };

    // 4 tiles of 4 steps; A 2 tiles ahead, B fully resident
    comp4(T0, 0); refill(T0, 2);
    comp4(T1, 1); refill(T1, 3);
    comp4(T0, 2);
    comp4(T1, 3);

    // ---- cross-wave reduce: C row = 4*u4 + reg (= b), col = r16 ----
    {
        float* red = (float*)lds + wv * 128;
        if (u4 < 2) {
            #pragma unroll
            for (int r = 0; r < 4; ++r)
                red[(u4 * 4 + r) * 16 + r16] = acc[r];
        }
    }
    __syncthreads();
    if (tid < 128) {
        const float* rd = (const float*)lds;
        float sm = 0.0f;
        #pragma unroll
        for (int wi = 0; wi < NWV; ++wi)
            sm += rd[wi * 128 + tid];
        out[(tid >> 4) * 8192 + n0 + (tid & 15)] = sm;
    }
}

extern "C" void kernel_launch(void* const* d_in, const int* in_sizes, int n_in,
                              void* d_out, int out_size, void* d_ws, size_t ws_size,
                              hipStream_t stream)
{
    const float* x = (const float*)d_in[0];
    const int*   q = (const int*)d_in[1];
    float* out = (float*)d_out;
    char*  tbl = (char*)d_ws;              // 256*528 = 135168 B

    hipLaunchKernelGGL(build_atable, dim3(256), dim3(64), 0, stream, x, tbl);
    hipLaunchKernelGGL(hi4b_gemm, dim3(512), dim3(1024), LDS_BYTES, stream,
                       tbl, q, out);
}